// Round 1
// baseline (422.799 us; speedup 1.0000x reference)
//
#include <hip/hip_runtime.h>

// QuantumGate: apply 4x4 gate matrix to qubits (q0, q1) of a (BATCH, 2^24) fp32 state.
// Qubit q  <->  bit (TOTAL_QUBITS-1-q) of the flat index.
// Gate index k = 2*bit(q0) + bit(q1).
// Memory-bound: each element read once, written once (537 MB total traffic).

#define TOTAL_QUBITS 24
#define DIM (1u << TOTAL_QUBITS)
#define BATCH 4

__global__ __launch_bounds__(256) void quantum_gate_kernel(
    const float* __restrict__ state,
    const float* __restrict__ matrix,
    const int* __restrict__ q0p,
    const int* __restrict__ q1p,
    float* __restrict__ out)
{
    const int q0 = q0p[0];
    const int q1 = q1p[0];
    const int p0 = TOTAL_QUBITS - 1 - q0;   // bit position of gate-index MSB
    const int p1 = TOTAL_QUBITS - 1 - q1;   // bit position of gate-index LSB
    const int p_lo = (p0 < p1) ? p0 : p1;
    const int p_hi = (p0 < p1) ? p1 : p0;

    // 4x4 gate matrix -> registers (uniform broadcast load, L2-cached)
    float m[16];
#pragma unroll
    for (int i = 0; i < 16; ++i) m[i] = matrix[i];

    // One thread = one float4 group of base indices (both gate bits cleared).
    // Per batch: 2^24 / 4 (gate states) / 4 (float4) = 2^20 threads.
    const unsigned gid   = blockIdx.x * blockDim.x + threadIdx.x;
    const unsigned batch = gid >> (TOTAL_QUBITS - 4);          // gid / 2^20
    const unsigned vec   = gid & ((1u << (TOTAL_QUBITS - 4)) - 1);
    unsigned t = vec << 2;                                     // 22-bit compact index, low2=0

    // Expand: insert a zero bit at p_lo, then at p_hi (p_lo < p_hi, both >= 2
    // for the given q0=3,q1=10 -> float4 alignment preserved).
    t = ((t >> p_lo) << (p_lo + 1)) | (t & ((1u << p_lo) - 1));
    t = ((t >> p_hi) << (p_hi + 1)) | (t & ((1u << p_hi) - 1));

    const size_t base = (size_t)batch * DIM + t;
    const size_t o_msb = (size_t)1 << p0;   // offset toggling gate-index bit 1
    const size_t o_lsb = (size_t)1 << p1;   // offset toggling gate-index bit 0

    float4 sv[4];
    sv[0] = *(const float4*)(state + base);                 // k = 0
    sv[1] = *(const float4*)(state + base + o_lsb);         // k = 1
    sv[2] = *(const float4*)(state + base + o_msb);         // k = 2
    sv[3] = *(const float4*)(state + base + o_msb + o_lsb); // k = 3

    // View as s[k][lane]
    float s[4][4];
#pragma unroll
    for (int k = 0; k < 4; ++k) {
        s[k][0] = sv[k].x; s[k][1] = sv[k].y; s[k][2] = sv[k].z; s[k][3] = sv[k].w;
    }

    float4 rv[4];
#pragma unroll
    for (int g = 0; g < 4; ++g) {
        float r[4];
#pragma unroll
        for (int lane = 0; lane < 4; ++lane) {
            r[lane] = m[g * 4 + 0] * s[0][lane]
                    + m[g * 4 + 1] * s[1][lane]
                    + m[g * 4 + 2] * s[2][lane]
                    + m[g * 4 + 3] * s[3][lane];
        }
        rv[g].x = r[0]; rv[g].y = r[1]; rv[g].z = r[2]; rv[g].w = r[3];
    }

    *(float4*)(out + base)                 = rv[0];
    *(float4*)(out + base + o_lsb)         = rv[1];
    *(float4*)(out + base + o_msb)         = rv[2];
    *(float4*)(out + base + o_msb + o_lsb) = rv[3];
}

extern "C" void kernel_launch(void* const* d_in, const int* in_sizes, int n_in,
                              void* d_out, int out_size, void* d_ws, size_t ws_size,
                              hipStream_t stream) {
    const float* state  = (const float*)d_in[0];
    const float* matrix = (const float*)d_in[1];
    const int*   q0     = (const int*)d_in[2];
    const int*   q1     = (const int*)d_in[3];
    float*       out    = (float*)d_out;

    // BATCH * 2^20 threads, 256/block
    const unsigned total_threads = BATCH << (TOTAL_QUBITS - 4);
    const unsigned blocks = total_threads / 256;
    quantum_gate_kernel<<<blocks, 256, 0, stream>>>(state, matrix, q0, q1, out);
}